// Round 2
// baseline (163.762 us; speedup 1.0000x reference)
//
#include <hip/hip_runtime.h>
#include <hip/hip_bf16.h>

// Problem constants (from reference): E=4 edge types, B=262144 tokens, C=128 dim
#define N_E 4
#define N_B 262144
#define N_C 128

typedef __attribute__((ext_vector_type(8))) short bf16x8;   // 8 bf16 = 4 VGPRs (MFMA A/B frag)
typedef __attribute__((ext_vector_type(4))) float f32x4;    // MFMA C/D frag
typedef __attribute__((ext_vector_type(4))) unsigned int u32x4;

// pack two fp32 -> one u32 of 2 bf16 (RNE) via v_cvt_pk_bf16_f32
__device__ __forceinline__ unsigned pk2(float lo, float hi) {
  float2 t; t.x = lo; t.y = hi;
  __hip_bfloat162 h = __float22bfloat162_rn(t);
  union { __hip_bfloat162 h; unsigned u; } c;
  c.h = h;
  return c.u;  // low 16 bits = lo
}

// out[b][d] = sum_e sum_c xs[e][b][c]*Ws[e][c][d] + sum_e bs[e][d]
// GEMM: M=262144, N=128, K=512. Memory-bound: stream xs once at HBM rate.
//
// Structure: 512 threads = 8 waves; wave w owns rows [blk*128+w*16, +16) x 128 cols.
// ALL 4 W matrices staged once into 128 KiB LDS (bf16, fragment-ready 16B entries)
// -> exactly ONE __syncthreads in the kernel; the 16-step main loop has no barriers,
// so xs loads pipeline freely across the whole e x kt space (no vmcnt(0) drains).
// LDS entry (e, u, d): 8 bf16 at k=u*8+j of Ws[e][.][d]; 16-lane groups read 256B
// contiguous -> b128 reads at the 8-words/bank floor (no conflicts).
__global__ void __launch_bounds__(512, 2)
grouped_gemm(const float* __restrict__ xs, const float* __restrict__ Ws,
             const float* __restrict__ bs, float* __restrict__ out) {
  extern __shared__ unsigned char smem[];
  unsigned short* lds_w  = (unsigned short*)smem;            // 8192 entries * 16B = 128 KiB
  float*          lds_bias = (float*)(smem + N_E * 16 * 128 * 16);

  const int tid  = threadIdx.x;
  const int lane = tid & 63;
  const int wave = tid >> 6;       // 0..7
  const int l15  = lane & 15;      // row-within-tile (A) / col-within-frag (B)
  const int hi   = lane >> 4;      // 0..3: k-subgroup

  // ---- stage ALL W (4 x 128 x 128 fp32) -> LDS bf16, fragment layout (once) ----
  // 8192 entries of 16B; 512 threads x 16 entries. Entry m: e=m>>11, u=(m>>7)&15, d=m&127.
#pragma unroll
  for (int i = 0; i < 16; ++i) {
    int m = tid + i * 512;
    int e = m >> 11;
    int u = (m >> 7) & 15;
    int d = m & 127;
    const float* src = Ws + e * (N_C * N_C) + u * 8 * N_C + d;  // coalesced across lanes (d consec)
    float v[8];
#pragma unroll
    for (int j = 0; j < 8; ++j) v[j] = src[j * N_C];
    u32x4 pk;
#pragma unroll
    for (int j = 0; j < 4; ++j) pk[j] = pk2(v[2 * j], v[2 * j + 1]);
    *reinterpret_cast<u32x4*>(&lds_w[(size_t)m * 8]) = pk;  // contiguous 16B/lane: conflict-free
  }
  if (tid < 128) {
    lds_bias[tid] = bs[tid] + bs[128 + tid] + bs[256 + tid] + bs[384 + tid];
  }
  __syncthreads();   // the ONLY barrier

  const int waveRow = blockIdx.x * 128 + wave * 16;

  f32x4 acc[8];
#pragma unroll
  for (int n = 0; n < 8; ++n) {
    f32x4 z = {0.0f, 0.0f, 0.0f, 0.0f};
    acc[n] = z;
  }

  // lane's A row pointer (row = waveRow + l15)
  const float* xrow = xs + (size_t)(waveRow + l15) * N_C;

#pragma unroll
  for (int e = 0; e < N_E; ++e) {
    const float* xe = xrow + (size_t)e * N_B * N_C;
#pragma unroll
    for (int kt = 0; kt < 4; ++kt) {
      // A frag: lane holds xs[e][waveRow+l15][kt*32 + hi*8 + 0..7] (32B contiguous)
      const float* ap = xe + kt * 32 + hi * 8;
      f32x4 a0 = *reinterpret_cast<const f32x4*>(ap);
      f32x4 a1 = *reinterpret_cast<const f32x4*>(ap + 4);
      bf16x8 afrag;
      unsigned* au = reinterpret_cast<unsigned*>(&afrag);
      au[0] = pk2(a0[0], a0[1]);
      au[1] = pk2(a0[2], a0[3]);
      au[2] = pk2(a1[0], a1[1]);
      au[3] = pk2(a1[2], a1[3]);
      // B frags: one ds_read_b128 each; entry index ((e*16 + kt*4 + hi)*128 + n*16 + l15)
      const unsigned short* wb = &lds_w[(size_t)((e * 16 + kt * 4 + hi) * 128 + l15) * 8];
#pragma unroll
      for (int n = 0; n < 8; ++n) {
        bf16x8 bfrag = *reinterpret_cast<const bf16x8*>(wb + (size_t)n * 16 * 8);
        acc[n] = __builtin_amdgcn_mfma_f32_16x16x32_bf16(afrag, bfrag, acc[n], 0, 0, 0);
      }
    }
  }

  // ---- epilogue: + bias, store. C/D layout: col = lane&15, row = (lane>>4)*4 + reg ----
#pragma unroll
  for (int n = 0; n < 8; ++n) {
    int d = n * 16 + l15;
    float bias = lds_bias[d];
#pragma unroll
    for (int r = 0; r < 4; ++r) {
      int row = waveRow + hi * 4 + r;
      out[(size_t)row * N_C + d] = acc[n][r] + bias;
    }
  }
}

extern "C" void kernel_launch(void* const* d_in, const int* in_sizes, int n_in,
                              void* d_out, int out_size, void* d_ws, size_t ws_size,
                              hipStream_t stream) {
  const float* xs = (const float*)d_in[0];  // [4][262144][128] fp32
  const float* Ws = (const float*)d_in[1];  // [4][128][128] fp32
  const float* bs = (const float*)d_in[2];  // [4][128] fp32
  float* out = (float*)d_out;               // [262144][128] fp32

  const size_t smem = (size_t)N_E * 16 * 128 * 16 + 128 * sizeof(float);  // 131584 B
  // dynamic LDS > 64 KiB needs the attribute raised (HK-proven path on gfx950)
  hipFuncSetAttribute((const void*)grouped_gemm,
                      hipFuncAttributeMaxDynamicSharedMemorySize, (int)smem);

  dim3 grid(N_B / 128);   // 2048 blocks, no tail
  dim3 block(512);
  hipLaunchKernelGGL(grouped_gemm, grid, block, smem, stream, xs, Ws, bs, out);
}

// Round 3
// 154.985 us; speedup vs baseline: 1.0566x; 1.0566x over previous
//
#include <hip/hip_runtime.h>
#include <hip/hip_bf16.h>

// Problem constants: E=4 edge types, B=262144 tokens, C=128 dim
#define N_E 4
#define N_B 262144
#define N_C 128

typedef __attribute__((ext_vector_type(8))) short bf16x8;   // MFMA A/B frag (8 bf16)
typedef __attribute__((ext_vector_type(4))) float f32x4;    // MFMA C/D frag
typedef __attribute__((ext_vector_type(4))) unsigned int u32x4;

// pack two fp32 -> u32 of 2 bf16 (RNE) via v_cvt_pk_bf16_f32
__device__ __forceinline__ unsigned pk2(float lo, float hi) {
  float2 t; t.x = lo; t.y = hi;
  __hip_bfloat162 h = __float22bfloat162_rn(t);
  union { __hip_bfloat162 h; unsigned u; } c;
  c.h = h;
  return c.u;
}

// async global->LDS, 16B per lane; LDS dest is wave-uniform base + lane*16 (HW rule)
__device__ __forceinline__ void gload_lds16(const float* g, void* l) {
  __builtin_amdgcn_global_load_lds((const __attribute__((address_space(1))) void*)g,
                                   (__attribute__((address_space(3))) void*)l,
                                   16, 0, 0);
}

// out[b][d] = sum_e sum_c xs[e][b][c]*Ws[e][c][d] + sum_e bs[e][d]
// M=262144, N=128, K=512; memory-bound: stream xs once at full HBM rate.
//
// 512 threads = 8 waves; wave w owns rows [blk*128+w*16,+16). Per (e,kt) step a wave
// stages its 16 rows x 128B chunk via 2x global_load_lds (1KB lane-contiguous each:
// 8 fully-consumed cache lines/instr — copy-kernel pattern). 2-deep per-wave double
// buffer, counted vmcnt(2) (never 0 until last step), NO barriers in the main loop.
// A-chunk XOR swizzle (byte ^= (row&7)<<4): applied to the GLOBAL source (stays
// within each 128B line -> coalescing intact) and to the ds_read address -> readers
// spread evenly over all 8 16B granules (no bank conflicts).
// W (all 4 matrices) LDS-resident in bf16 fragment layout; one barrier total.
__global__ void __launch_bounds__(512, 2)
grouped_gemm(const float* __restrict__ xs, const float* __restrict__ Ws,
             const float* __restrict__ bs, float* __restrict__ out) {
  extern __shared__ unsigned char smem[];
  unsigned short* lds_w = (unsigned short*)smem;     // 4*16*128 entries * 16B = 128 KiB
  unsigned char*  lds_a = smem + 131072;             // 8 waves * 2 bufs * 2 KiB = 32 KiB

  const int tid  = threadIdx.x;
  const int lane = tid & 63;
  const int wave = tid >> 6;
  const int l15  = lane & 15;
  const int hi   = lane >> 4;
  const int waveRow = blockIdx.x * 128 + wave * 16;

  // ---- bias -> registers (pre-barrier; __syncthreads drains the loads) ----
  float bias[8];
#pragma unroll
  for (int n = 0; n < 8; ++n) {
    int d = n * 16 + l15;
    bias[n] = bs[d] + bs[128 + d] + bs[256 + d] + bs[384 + d];
  }

  // ---- stage ALL W (4x128x128 fp32) -> LDS bf16 fragment layout (once) ----
  // 8192 entries of 16B; entry m: e=m>>11, u=(m>>7)&15, d=m&127.
#pragma unroll
  for (int i = 0; i < 16; ++i) {
    int m = tid + i * 512;
    int e = m >> 11;
    int u = (m >> 7) & 15;
    int d = m & 127;
    const float* src = Ws + e * (N_C * N_C) + u * 8 * N_C + d;
    float v[8];
#pragma unroll
    for (int j = 0; j < 8; ++j) v[j] = src[j * N_C];
    u32x4 pk;
#pragma unroll
    for (int j = 0; j < 4; ++j) pk[j] = pk2(v[2 * j], v[2 * j + 1]);
    *reinterpret_cast<u32x4*>(&lds_w[(size_t)m * 8]) = pk;
  }
  __syncthreads();  // the only barrier: W published, all vmem drained (vmcnt clean)

  // ---- per-lane staging invariants ----
  // stage instr s2 (0/1), lane: row = s2*8 + (lane>>3); within-row float = wq
  // where wq = ((lane&7) ^ (lane>>3)) * 4  (inverse of the read-side XOR swizzle)
  const int r0 = lane >> 3;
  const int wq = (((lane & 7) ^ r0) << 2);
  const float* srcbase = xs + (size_t)(waveRow + r0) * N_C + wq;
  unsigned char* abase = lds_a + wave * 4096;

  // reader: lane (l15,hi) reads bytes (hi*32 + h*16) ^ ((l15&7)<<4) of row l15
  const int rdoff = l15 * 128 + ((hi * 32) ^ ((l15 & 7) << 4));

  f32x4 acc[8];
#pragma unroll
  for (int n = 0; n < 8; ++n) {
    f32x4 z = {0.0f, 0.0f, 0.0f, 0.0f};
    acc[n] = z;
  }

  // STAGE(s): chunk s (e=s>>2, kt=s&3) -> buf s&1 (2 x 1KB global_load_lds)
#define STAGE(s)                                                            \
  do {                                                                      \
    const float* g = srcbase + (size_t)((s) >> 2) * (N_B * N_C) + ((s) & 3) * 32; \
    unsigned char* l = abase + ((s) & 1) * 2048;                            \
    gload_lds16(g, l);                                                      \
    gload_lds16(g + 8 * N_C, l + 1024);                                     \
  } while (0)

  STAGE(0);
  STAGE(1);

#pragma unroll
  for (int s = 0; s < 16; ++s) {
    const int e = s >> 2, kt = s & 3, b = s & 1;

    // wait for stage(s); keep stage(s+1)'s 2 loads in flight (counted, not 0)
    if (s < 15) {
      asm volatile("s_waitcnt vmcnt(2)" ::: "memory");
    } else {
      asm volatile("s_waitcnt vmcnt(0)" ::: "memory");
    }
    __builtin_amdgcn_sched_barrier(0);

    // A frag from LDS (swizzled), convert to bf16
    const unsigned char* ab = abase + b * 2048;
    f32x4 a0 = *reinterpret_cast<const f32x4*>(ab + rdoff);         // floats hi*8+0..3
    f32x4 a1 = *reinterpret_cast<const f32x4*>(ab + (rdoff ^ 16));  // floats hi*8+4..7
    bf16x8 afrag;
    unsigned* au = reinterpret_cast<unsigned*>(&afrag);
    au[0] = pk2(a0[0], a0[1]);
    au[1] = pk2(a0[2], a0[3]);
    au[2] = pk2(a1[0], a1[1]);
    au[3] = pk2(a1[2], a1[3]);

    // make sure this step's A ds_reads retired before overwriting buf b, then prefetch
    asm volatile("s_waitcnt lgkmcnt(0)" ::: "memory");
    __builtin_amdgcn_sched_barrier(0);
    if (s < 14) STAGE(s + 2);

    // B frags from W-LDS + MFMA
    const unsigned short* wb = lds_w + (size_t)((e * 16 + kt * 4 + hi) * 128 + l15) * 8;
#pragma unroll
    for (int n = 0; n < 8; ++n) {
      bf16x8 bfrag = *reinterpret_cast<const bf16x8*>(wb + (size_t)n * 128);
      acc[n] = __builtin_amdgcn_mfma_f32_16x16x32_bf16(afrag, bfrag, acc[n], 0, 0, 0);
    }
  }
#undef STAGE

  // ---- epilogue: + bias, store. C/D: col = lane&15, row = (lane>>4)*4 + reg ----
#pragma unroll
  for (int n = 0; n < 8; ++n) {
    int d = n * 16 + l15;
#pragma unroll
    for (int r = 0; r < 4; ++r) {
      int row = waveRow + hi * 4 + r;
      out[(size_t)row * N_C + d] = acc[n][r] + bias[n];
    }
  }
}

extern "C" void kernel_launch(void* const* d_in, const int* in_sizes, int n_in,
                              void* d_out, int out_size, void* d_ws, size_t ws_size,
                              hipStream_t stream) {
  const float* xs = (const float*)d_in[0];  // [4][262144][128] fp32
  const float* Ws = (const float*)d_in[1];  // [4][128][128] fp32
  const float* bs = (const float*)d_in[2];  // [4][128] fp32
  float* out = (float*)d_out;               // [262144][128] fp32

  const size_t smem = 131072 + 32768;  // W 128 KiB + A staging 32 KiB = 160 KiB exactly
  hipFuncSetAttribute((const void*)grouped_gemm,
                      hipFuncAttributeMaxDynamicSharedMemorySize, (int)smem);

  dim3 grid(N_B / 128);  // 2048 blocks
  dim3 block(512);
  hipLaunchKernelGGL(grouped_gemm, grid, block, smem, stream, xs, Ws, bs, out);
}

// Round 4
// 145.891 us; speedup vs baseline: 1.1225x; 1.0623x over previous
//
#include <hip/hip_runtime.h>
#include <hip/hip_bf16.h>

// Problem constants: E=4 edge types, B=262144 tokens, C=128 dim
#define N_E 4
#define N_B 262144
#define N_C 128

typedef __attribute__((ext_vector_type(8))) short bf16x8;   // MFMA A/B frag (8 bf16)
typedef __attribute__((ext_vector_type(4))) float f32x4;    // MFMA C/D frag
typedef __attribute__((ext_vector_type(4))) unsigned int u32x4;

// pack two fp32 -> u32 of 2 bf16 (RNE) via v_cvt_pk_bf16_f32
__device__ __forceinline__ unsigned pk2(float lo, float hi) {
  float2 t; t.x = lo; t.y = hi;
  __hip_bfloat162 h = __float22bfloat162_rn(t);
  union { __hip_bfloat162 h; unsigned u; } c;
  c.h = h;
  return c.u;
}

// out[b][d] = sum_e sum_c xs[e][b][c]*Ws[e][c][d] + sum_e bs[e][d]
// M=262144, N=128, K=512; memory-bound. Rounds 1-3 all pinned at ~4.2 TB/s with
// <=32 KB/CU of loads in flight (LDS-capacity-capped pipelines). This version puts
// the xs stream entirely in REGISTERS with a 4-deep manually-counted pipeline:
//   16 waves/CU x 4 chunks x 2 KB = 128 KB/CU in flight (4x round 3).
// The ONLY vmem ops in the main loop are our inline-asm loads, so vmcnt counts are
// exact: steady-state s_waitcnt vmcnt(6), tail 4/2/0, sched_barrier(0) after each
// wait (hipcc hoists VALU past asm waitcnt otherwise). No barriers in the loop.
// W (all 4 e) lives in LDS bf16 fragment layout (128 KiB), staged once.
__global__ void __launch_bounds__(1024, 4)
grouped_gemm(const float* __restrict__ xs, const float* __restrict__ Ws,
             const float* __restrict__ bs, float* __restrict__ out) {
  extern __shared__ unsigned char smem[];
  unsigned short* lds_w = (unsigned short*)smem;  // 8192 entries * 16B = 128 KiB

  const int tid  = threadIdx.x;
  const int lane = tid & 63;
  const int wave = tid >> 6;       // 0..15
  const int l15  = lane & 15;
  const int hi   = lane >> 4;
  const int waveRow = blockIdx.x * 256 + wave * 16;

  // ---- bias -> registers (must retire before the A-pipeline region) ----
  float bias[8];
#pragma unroll
  for (int n = 0; n < 8; ++n) {
    int d = n * 16 + l15;
    bias[n] = bs[d] + bs[128 + d] + bs[256 + d] + bs[384 + d];
  }

  // ---- stage ALL W (4x128x128 fp32) -> LDS bf16 fragment layout (once) ----
  // entry m: e=m>>11, u=(m>>7)&15, d=m&127 ; holds Ws[e][u*8+j][d], j=0..7 (16B)
#pragma unroll
  for (int i = 0; i < 8; ++i) {
    int m = tid + i * 1024;
    int e = m >> 11;
    int u = (m >> 7) & 15;
    int d = m & 127;
    const float* src = Ws + e * (N_C * N_C) + u * 8 * N_C + d;
    float v[8];
#pragma unroll
    for (int j = 0; j < 8; ++j) v[j] = src[j * N_C];
    u32x4 pk;
#pragma unroll
    for (int j = 0; j < 4; ++j) pk[j] = pk2(v[2 * j], v[2 * j + 1]);
    *reinterpret_cast<u32x4*>(&lds_w[(size_t)m * 8]) = pk;
  }

  // Drain ALL compiler-emitted vmem (bias + W gather) so loop vmcnt counts are exact.
  asm volatile("s_waitcnt vmcnt(0)" ::: "memory");
  __syncthreads();  // the only barrier

  // ---- A stream: 16 chunks (e=s>>2, kt=s&3); lane reads 32B of row waveRow+l15 ----
  // byte offset in xs: (waveRow+l15)*512 + e*134217728 + kt*128 + hi*32 (+16 for a1)
  const unsigned vb = (unsigned)(waveRow + l15) * 512u + (unsigned)hi * 32u;
  const unsigned long long xbase = (unsigned long long)xs;

  f32x4 A0[4], A1[4];  // 4-deep rotating chunk buffer (statically indexed only)

#define AISSUE(c)                                                              \
  do {                                                                         \
    unsigned o;                                                                \
    asm volatile("v_add_u32 %0, %1, %2"                                        \
                 : "=v"(o)                                                     \
                 : "n"(((c) >> 2) * 134217728u + ((c) & 3) * 128u), "v"(vb));  \
    asm volatile("global_load_dwordx4 %0, %2, %3 offset:0\n\t"                 \
                 "global_load_dwordx4 %1, %2, %3 offset:16"                    \
                 : "=&v"(A0[(c) & 3]), "=&v"(A1[(c) & 3])                      \
                 : "v"(o), "s"(xbase)                                          \
                 : "memory");                                                  \
  } while (0)

#define WAITV(n)                                  \
  do {                                            \
    asm volatile("s_waitcnt vmcnt(" #n ")" ::: "memory"); \
    __builtin_amdgcn_sched_barrier(0);            \
  } while (0)

  f32x4 acc[8];
#pragma unroll
  for (int n = 0; n < 8; ++n) {
    f32x4 z = {0.0f, 0.0f, 0.0f, 0.0f};
    acc[n] = z;
  }

  AISSUE(0); AISSUE(1); AISSUE(2); AISSUE(3);

  // STEP(s): wait chunk s, convert, refill slot, 8 x MFMA against LDS-resident W
#define STEP(s, w)                                                             \
  do {                                                                         \
    WAITV(w);                                                                  \
    f32x4 a0 = A0[(s) & 3];                                                    \
    f32x4 a1 = A1[(s) & 3];                                                    \
    bf16x8 afrag;                                                              \
    unsigned* au = reinterpret_cast<unsigned*>(&afrag);                        \
    au[0] = pk2(a0[0], a0[1]);                                                 \
    au[1] = pk2(a0[2], a0[3]);                                                 \
    au[2] = pk2(a1[0], a1[1]);                                                 \
    au[3] = pk2(a1[2], a1[3]);                                                 \
    if ((s) <= 11) AISSUE((s) + 4);                                            \
    const unsigned short* wb =                                                 \
        lds_w + (size_t)((((s) >> 2) * 16 + ((s) & 3) * 4 + hi) * 128 + l15) * 8; \
    _Pragma("unroll")                                                          \
    for (int n = 0; n < 8; ++n) {                                              \
      bf16x8 bfrag = *reinterpret_cast<const bf16x8*>(wb + (size_t)n * 128);   \
      acc[n] = __builtin_amdgcn_mfma_f32_16x16x32_bf16(afrag, bfrag, acc[n], 0, 0, 0); \
    }                                                                          \
  } while (0)

  STEP(0, 6);  STEP(1, 6);  STEP(2, 6);  STEP(3, 6);
  STEP(4, 6);  STEP(5, 6);  STEP(6, 6);  STEP(7, 6);
  STEP(8, 6);  STEP(9, 6);  STEP(10, 6); STEP(11, 6);
  STEP(12, 6); STEP(13, 4); STEP(14, 2); STEP(15, 0);

#undef STEP
#undef WAITV
#undef AISSUE

  // ---- epilogue: + bias, store. C/D: col = lane&15, row = (lane>>4)*4 + reg ----
#pragma unroll
  for (int n = 0; n < 8; ++n) {
    int d = n * 16 + l15;
#pragma unroll
    for (int r = 0; r < 4; ++r) {
      int row = waveRow + hi * 4 + r;
      out[(size_t)row * N_C + d] = acc[n][r] + bias[n];
    }
  }
}

extern "C" void kernel_launch(void* const* d_in, const int* in_sizes, int n_in,
                              void* d_out, int out_size, void* d_ws, size_t ws_size,
                              hipStream_t stream) {
  const float* xs = (const float*)d_in[0];  // [4][262144][128] fp32
  const float* Ws = (const float*)d_in[1];  // [4][128][128] fp32
  const float* bs = (const float*)d_in[2];  // [4][128] fp32
  float* out = (float*)d_out;               // [262144][128] fp32

  const size_t smem = 131072;  // W bf16 frag layout, all 4 edge types
  hipFuncSetAttribute((const void*)grouped_gemm,
                      hipFuncAttributeMaxDynamicSharedMemorySize, (int)smem);

  dim3 grid(N_B / 256);   // 1024 blocks (256 rows each), 4 generations/CU
  dim3 block(1024);       // 16 waves -> 16 waves/CU (VGPR capped at 128)
  hipLaunchKernelGGL(grouped_gemm, grid, block, smem, stream, xs, Ws, bs, out);
}